// Round 6
// baseline (252.931 us; speedup 1.0000x reference)
//
#include <hip/hip_runtime.h>
#include <hip/hip_bf16.h>

// Transposed conv (full conv): out[b,p,q,co] = sum_{kh,kw,ci} in[b,p-kh,q-kw,ci]*K[ci,co,kh,kw]
// B=8 H=W=256 C=64, out 8x258x258x64 fp32. bf16 MFMA path.
//
// R6 = R5 + raw-barrier sync (T4 discipline). R5 post-mortem: __syncthreads()
// lowers to s_waitcnt vmcnt(0) lgkmcnt(0) + s_barrier -> every tile serially
// drained the 8 epilogue stores (131KB HBM, ~2.2us) and the prefetch load tail
// at the top-of-loop barrier, defeating the prefetch overlap. Raw s_barrier with
// minimal waits: barrier A (before commit) = s_barrier only (compute's ds_reads
// already consumed; load->commit deps are compiler-counted and older than the
// stores); barrier B (after commit) = lgkmcnt(0) + s_barrier (lds_in RAW).
// Stores are fire-and-forget until kernel end. Also: tap loop unroll 3 so the
// scheduler hoists next-tap ds_reads under current MFMAs.
// Weight layout (conflict-free 256B/16-lane), XOR patch swizzle, persistent
// 256-block grid, transposed-D epilogue: identical to verified R5.

#define OH 258
#define OW 258

typedef __bf16 bf16x8 __attribute__((ext_vector_type(8)));
typedef float  f32x4  __attribute__((ext_vector_type(4)));

// ws layout (conflict-free): wsW[(((tap*2+s)*4+nt)*512) + h*128 + ml*8 + j]
//   = K[ci=32s+8h+j][co=16nt+ml][kh][kw],  tap=kh*3+kw
__global__ void prep_w_kernel(const float* __restrict__ k, __bf16* __restrict__ wsW) {
    int i = blockIdx.x * 256 + threadIdx.x;            // [0, 36864)
    int j  = i & 7;
    int ml = (i >> 3) & 15;
    int h  = (i >> 7) & 3;
    int nt = (i >> 9) & 3;
    int st = i >> 11;                                  // [0,18)
    int s  = st & 1, tap = st >> 1;
    int ci = s * 32 + h * 8 + j;
    int co = nt * 16 + ml;
    wsW[i] = (__bf16)k[ci * 576 + co * 9 + tap];
}

__device__ __forceinline__ void tile_coords(int tau, int& b, int& p0, int& q0) {
    int bb = tau / 153;                                // 153 = 9 p-tiles * 17 q-tiles
    int rr = tau - bb * 153;
    int py = rr / 17;
    b  = bb;
    p0 = py * 32;
    q0 = (rr - py * 17) * 16;
}

// issue the 10 guarded global loads for one tile's 34x18 patch into regs
__device__ __forceinline__ void issue_patch_loads(
        const float* __restrict__ in, int b, int p0, int q0, int tid,
        f32x4 (&v0)[5], f32x4 (&v1)[5]) {
    #pragma unroll
    for (int k = 0; k < 5; ++k) {
        const int it = tid + k * 1024;                 // granule id, < 4896
        const bool act = (k < 4) || (tid < 800);
        int pix = it >> 3, c8 = it & 7;
        int r = pix / 18, c = pix - r * 18;
        int ip = p0 - 2 + r, iq = q0 - 2 + c;
        f32x4 z = {0.f, 0.f, 0.f, 0.f};
        v0[k] = z; v1[k] = z;
        if (act && (unsigned)ip < 256u && (unsigned)iq < 256u) {
            const float* g = in + (((size_t)b * 256 + ip) * 256 + iq) * 64 + c8 * 8;
            v0[k] = *(const f32x4*)g;
            v1[k] = *(const f32x4*)(g + 4);
        }
    }
}

__global__ __launch_bounds__(1024, 4)
void tconv_kernel(const float* __restrict__ in, const __bf16* __restrict__ wsW,
                  float* __restrict__ out) {
    // input patch [pix=34*18][64ci] bf16, 16B granules XOR-swizzled by pix&7
    __shared__ __bf16 lds_in[612 * 64];   // 78336 B
    __shared__ __bf16 lds_w[36864];       // 73728 B ; 152064 total -> 1 block/CU

    const int tid = threadIdx.x;

    // ---- stage weights ONCE per block (linear bf16 copy, 4.5 iters)
    #pragma unroll
    for (int k = 0; k < 5; ++k) {
        const int g = tid + k * 1024;
        if ((k < 4) || (tid < 512))
            *(bf16x8*)&lds_w[(size_t)g * 8] = *(const bf16x8*)&wsW[(size_t)g * 8];
    }

    const int wv = tid >> 6, lane = tid & 63;
    const int ml = lane & 15, h = lane >> 4;
    const int woff = h * 128 + ml * 8;     // weight frag lane offset (conflict-free)
    const int rbase = wv * 2;              // wave's 2 rows of the 32

    // persistent: block bx handles tiles tau = bx + 256*t, tau < 1224
    const int bx = blockIdx.x;
    const int n_t = (bx < 200) ? 5 : 4;    // 200*5 + 56*4 = 1224

    int cb, cp0, cq0;
    tile_coords(bx, cb, cp0, cq0);
    f32x4 v0[5], v1[5];
    issue_patch_loads(in, cb, cp0, cq0, tid, v0, v1);  // tile 0 in flight

    int nb = 0, np0 = 0, nq0 = 0;

    #pragma unroll 1
    for (int t = 0; t < n_t; ++t) {
        // ---- barrier A: all waves done READING lds_in (results consumed by
        // MFMAs pre-epilogue). No vmcnt drain: stores stay in flight; the
        // load->commit data deps below are compiler-counted waits.
        asm volatile("" ::: "memory");
        __builtin_amdgcn_s_barrier();

        // ---- commit prefetched regs -> LDS (cvt f32->bf16, swizzled write)
        #pragma unroll
        for (int k = 0; k < 5; ++k) {
            const int it = tid + k * 1024;
            if ((k < 4) || (tid < 800)) {
                int pix = it >> 3, c8 = it & 7;
                bf16x8 w;
                w[0]=(__bf16)v0[k][0]; w[1]=(__bf16)v0[k][1];
                w[2]=(__bf16)v0[k][2]; w[3]=(__bf16)v0[k][3];
                w[4]=(__bf16)v1[k][0]; w[5]=(__bf16)v1[k][1];
                w[6]=(__bf16)v1[k][2]; w[7]=(__bf16)v1[k][3];
                *(bf16x8*)&lds_in[pix * 64 + ((c8 ^ (pix & 7)) * 8)] = w;
            }
        }
        // ---- issue NEXT tile's global loads; they fly under this tile's compute
        if (t + 1 < n_t) {
            tile_coords(bx + (t + 1) * 256, nb, np0, nq0);
            issue_patch_loads(in, nb, np0, nq0, tid, v0, v1);
        }
        // ---- barrier B: own ds_writes complete (lgkmcnt 0), then barrier ->
        // all waves' lds_in (and, on t==0, lds_w) writes visible. No vmcnt.
        asm volatile("s_waitcnt lgkmcnt(0)" ::: "memory");
        __builtin_amdgcn_s_barrier();

        // ---- compute: pure ds_read + MFMA (A=weights, B=pixels -> D transposed)
        f32x4 acc[2][4] = {};   // mt = output row within wave's 2; nt = co/16
        #pragma unroll 3
        for (int tap = 0; tap < 9; ++tap) {
            const int kh = tap / 3, kw = tap - kh * 3;
            const __bf16* wt = lds_w + tap * 4096;
            #pragma unroll
            for (int s = 0; s < 2; ++s) {
                bf16x8 bfr[4];
                #pragma unroll
                for (int nt = 0; nt < 4; ++nt)
                    bfr[nt] = *(const bf16x8*)(wt + s * 2048 + nt * 512 + woff);
                const int j = s * 4 + h;               // 16B granule within pixel
                #pragma unroll
                for (int mt = 0; mt < 2; ++mt) {
                    int row = rbase + mt + 2 - kh;     // patch row, in [0,34)
                    int pix = row * 18 + (2 - kw) + ml;
                    bf16x8 afr = *(const bf16x8*)&lds_in[pix * 64 + ((j ^ (pix & 7)) * 8)];
                    #pragma unroll
                    for (int nt = 0; nt < 4; ++nt)
                        acc[mt][nt] = __builtin_amdgcn_mfma_f32_16x16x32_bf16(
                            bfr[nt], afr, acc[mt][nt], 0, 0, 0);
                }
            }
        }

        // ---- epilogue: D transposed: lane (ml,h) holds out[p][cq0+ml][nt*16+h*4..+3]
        // Stores are fire-and-forget: nothing in-loop waits on them.
        const int q = cq0 + ml;
        #pragma unroll
        for (int mt = 0; mt < 2; ++mt) {
            int p = cp0 + rbase + mt;
            if (p < OH && q < OW) {
                float* op = out + (((size_t)cb * OH + p) * OW + q) * 64 + h * 4;
                #pragma unroll
                for (int nt = 0; nt < 4; ++nt)
                    *(f32x4*)(op + nt * 16) = acc[mt][nt];
            }
        }
        cb = nb; cp0 = np0; cq0 = nq0;
    }
}

extern "C" void kernel_launch(void* const* d_in, const int* in_sizes, int n_in,
                              void* d_out, int out_size, void* d_ws, size_t ws_size,
                              hipStream_t stream) {
    (void)in_sizes; (void)n_in; (void)out_size; (void)ws_size;
    const float* in   = (const float*)d_in[0];
    const float* kern = (const float*)d_in[1];
    float* out = (float*)d_out;
    __bf16* wsW = (__bf16*)d_ws;   // 36864 bf16 = 73728 B

    prep_w_kernel<<<144, 256, 0, stream>>>(kern, wsW);
    tconv_kernel<<<256, 1024, 0, stream>>>(in, wsW, out);
}